// Round 1
// baseline (22.256 us; speedup 1.0000x reference)
//
#include <hip/hip_runtime.h>

// UserMerger — algebraic collapse:
//   mask = triu(MASK_VAL, k=0) masks the diagonal, so diag(softmax) == 0 for
//   rows m>=1 (exp underflow). Row 0 is fully masked; in fp32, Q_K + (-2^32)
//   rounds every entry to exactly -2^32 (|Q_K| << 128 = half-ulp), so softmax
//   is uniform and diag[b,0] == 1/1024 exactly.
//   => out[b,0,d] = sum_m user[b,m,d] / 1024 ; out[b,l>0,:] = 0.
//   W1,b1,W2,b2,hyper_embedding are dead inputs.

namespace {

constexpr int B  = 16;
constexpr int L  = 1024;
constexpr int D  = 512;
constexpr int MG  = 64;        // m-groups for phase-1 parallelism
constexpr int MPG = L / MG;    // 16 rows per group
constexpr int TPB = D / 4;     // 128 threads, one float4 (4 d's) each

// Phase 1: partial[b][g][d] = sum_{m in group g} user[b][m][d]
__global__ void partial_sum_kernel(const float* __restrict__ user,
                                   float* __restrict__ partial) {
    const int blk = blockIdx.x;            // b * MG + g
    const int b   = blk >> 6;              // / MG
    const int g   = blk & (MG - 1);        // % MG
    const int d4  = threadIdx.x;
    const float4* src = reinterpret_cast<const float4*>(
        user + (size_t)(b * L + g * MPG) * D) + d4;
    float4 acc = make_float4(0.f, 0.f, 0.f, 0.f);
#pragma unroll
    for (int m = 0; m < MPG; ++m) {
        float4 v = src[(size_t)m * (D / 4)];
        acc.x += v.x; acc.y += v.y; acc.z += v.z; acc.w += v.w;
    }
    reinterpret_cast<float4*>(partial + (size_t)(b * MG + g) * D)[d4] = acc;
}

// Phase 2: out[b,0,d] = (sum_g partial[b][g][d]) * (1/1024)
__global__ void fill_row0_kernel(const float* __restrict__ partial,
                                 float* __restrict__ out) {
    const int b  = blockIdx.x;
    const int d4 = threadIdx.x;
    const float4* p = reinterpret_cast<const float4*>(
        partial + (size_t)b * MG * D) + d4;
    float4 acc = make_float4(0.f, 0.f, 0.f, 0.f);
#pragma unroll 8
    for (int g = 0; g < MG; ++g) {
        float4 v = p[(size_t)g * (D / 4)];
        acc.x += v.x; acc.y += v.y; acc.z += v.z; acc.w += v.w;
    }
    const float s = 1.0f / 1024.0f;  // diag of softmax == uniform 1/L
    acc.x *= s; acc.y *= s; acc.z *= s; acc.w *= s;
    reinterpret_cast<float4*>(out + (size_t)b * L * D)[d4] = acc;
}

// Fallback (only if workspace is unexpectedly tiny): one block per batch does
// the whole reduction. Slower but correct.
__global__ void direct_row0_kernel(const float* __restrict__ user,
                                   float* __restrict__ out) {
    const int b  = blockIdx.x;
    const int d4 = threadIdx.x;
    const float4* src = reinterpret_cast<const float4*>(
        user + (size_t)b * L * D) + d4;
    float4 acc = make_float4(0.f, 0.f, 0.f, 0.f);
    for (int m = 0; m < L; ++m) {
        float4 v = src[(size_t)m * (D / 4)];
        acc.x += v.x; acc.y += v.y; acc.z += v.z; acc.w += v.w;
    }
    const float s = 1.0f / 1024.0f;
    acc.x *= s; acc.y *= s; acc.z *= s; acc.w *= s;
    reinterpret_cast<float4*>(out + (size_t)b * L * D)[d4] = acc;
}

} // namespace

extern "C" void kernel_launch(void* const* d_in, const int* in_sizes, int n_in,
                              void* d_out, int out_size, void* d_ws, size_t ws_size,
                              hipStream_t stream) {
    const float* user = (const float*)d_in[0];   // [B, L, D] fp32
    float* out = (float*)d_out;                  // [B, L, D] fp32

    // Zero the whole output (rows 1..L-1 are exactly zero).
    hipMemsetAsync(d_out, 0, (size_t)out_size * sizeof(float), stream);

    const size_t partial_bytes = (size_t)B * MG * D * sizeof(float); // 2 MiB
    if (ws_size >= partial_bytes) {
        float* partial = (float*)d_ws;
        partial_sum_kernel<<<B * MG, TPB, 0, stream>>>(user, partial);
        fill_row0_kernel<<<B, TPB, 0, stream>>>(partial, out);
    } else {
        direct_row0_kernel<<<B, TPB, 0, stream>>>(user, out);
    }
}

// Round 2
// 19.118 us; speedup vs baseline: 1.1641x; 1.1641x over previous
//
#include <hip/hip_runtime.h>

// UserMerger — algebraic collapse:
//   triu(MASK_VAL, k=0) masks the diagonal, so diag(softmax)==0 for rows m>=1
//   (exp underflow). Row 0 is fully masked; in fp32, Q_K + (-2^32) rounds every
//   entry to exactly -2^32 (|Q_K| << 128 = half-ulp at that magnitude), so the
//   row softmax is uniform and diag[b,0] == 1/1024 exactly.
//   => out[b,0,d] = sum_m user[b,m,d] / 1024 ; out[b,l>0,:] = 0.
//   W1,b1,W2,b2,hyper_embedding are dead inputs.
//
// R1: fuse the output zero-fill into the partial-sum pass (one 33.5MB-read +
// 33.5MB-write kernel) instead of a separate rocclr fillBuffer dispatch.

namespace {

constexpr int B   = 16;
constexpr int L   = 1024;
constexpr int D   = 512;
constexpr int MG  = 128;       // m-groups per batch (phase-1 blocks = B*MG = 2048)
constexpr int MPG = L / MG;    // 8 rows per group
constexpr int TPB = D / 4;     // 128 threads, one float4 (4 d's) each

// Phase 1: partial[b][g][d] = sum_{m in group g} user[b][m][d]
//          and out[b][m][:] = 0 for all m in group g.
__global__ void fused_zero_partial_kernel(const float* __restrict__ user,
                                          float* __restrict__ out,
                                          float* __restrict__ partial) {
    const int blk = blockIdx.x;            // b * MG + g
    const int b   = blk >> 7;              // / MG
    const int g   = blk & (MG - 1);        // % MG
    const int d4  = threadIdx.x;           // 0..127
    const size_t base = (size_t)(b * L + g * MPG) * D;
    const float4* src = reinterpret_cast<const float4*>(user + base) + d4;
    float4*       dst = reinterpret_cast<float4*>(out + base) + d4;
    const float4 z = make_float4(0.f, 0.f, 0.f, 0.f);
    float4 acc = z;
#pragma unroll
    for (int m = 0; m < MPG; ++m) {
        float4 v = src[(size_t)m * (D / 4)];
        acc.x += v.x; acc.y += v.y; acc.z += v.z; acc.w += v.w;
        dst[(size_t)m * (D / 4)] = z;      // row 0 gets overwritten in phase 2
    }
    reinterpret_cast<float4*>(partial + (size_t)(b * MG + g) * D)[d4] = acc;
}

// Phase 2: out[b,0,d] = (sum_g partial[b][g][d]) * (1/1024)
// 512 threads: 4-way split over groups + LDS combine.
__global__ void fill_row0_kernel(const float* __restrict__ partial,
                                 float* __restrict__ out) {
    const int b    = blockIdx.x;
    const int d4   = threadIdx.x & (TPB - 1);   // 0..127
    const int part = threadIdx.x >> 7;          // 0..3
    const float4* p = reinterpret_cast<const float4*>(
        partial + (size_t)(b * MG + part * (MG / 4)) * D) + d4;
    float4 acc = make_float4(0.f, 0.f, 0.f, 0.f);
#pragma unroll 8
    for (int g = 0; g < MG / 4; ++g) {
        float4 v = p[(size_t)g * (D / 4)];
        acc.x += v.x; acc.y += v.y; acc.z += v.z; acc.w += v.w;
    }
    __shared__ float4 sdata[4][TPB];
    sdata[part][d4] = acc;
    __syncthreads();
    if (part == 0) {
        float4 a0 = sdata[0][d4], a1 = sdata[1][d4];
        float4 a2 = sdata[2][d4], a3 = sdata[3][d4];
        const float s = 1.0f / 1024.0f;  // diag of softmax == uniform 1/L
        float4 r;
        r.x = (a0.x + a1.x + a2.x + a3.x) * s;
        r.y = (a0.y + a1.y + a2.y + a3.y) * s;
        r.z = (a0.z + a1.z + a2.z + a3.z) * s;
        r.w = (a0.w + a1.w + a2.w + a3.w) * s;
        reinterpret_cast<float4*>(out + (size_t)b * L * D)[d4] = r;
    }
}

// Fallback (only if workspace is unexpectedly tiny): memset + direct reduce.
__global__ void direct_row0_kernel(const float* __restrict__ user,
                                   float* __restrict__ out) {
    const int b  = blockIdx.x;
    const int d4 = threadIdx.x;
    const float4* src = reinterpret_cast<const float4*>(
        user + (size_t)b * L * D) + d4;
    float4 acc = make_float4(0.f, 0.f, 0.f, 0.f);
    for (int m = 0; m < L; ++m) {
        float4 v = src[(size_t)m * (D / 4)];
        acc.x += v.x; acc.y += v.y; acc.z += v.z; acc.w += v.w;
    }
    const float s = 1.0f / 1024.0f;
    acc.x *= s; acc.y *= s; acc.z *= s; acc.w *= s;
    reinterpret_cast<float4*>(out + (size_t)b * L * D)[d4] = acc;
}

} // namespace

extern "C" void kernel_launch(void* const* d_in, const int* in_sizes, int n_in,
                              void* d_out, int out_size, void* d_ws, size_t ws_size,
                              hipStream_t stream) {
    const float* user = (const float*)d_in[0];   // [B, L, D] fp32
    float* out = (float*)d_out;                  // [B, L, D] fp32

    const size_t partial_bytes = (size_t)B * MG * D * sizeof(float); // 4 MiB
    if (ws_size >= partial_bytes) {
        float* partial = (float*)d_ws;
        fused_zero_partial_kernel<<<B * MG, TPB, 0, stream>>>(user, out, partial);
        fill_row0_kernel<<<B, 4 * TPB, 0, stream>>>(partial, out);
    } else {
        hipMemsetAsync(d_out, 0, (size_t)out_size * sizeof(float), stream);
        direct_row0_kernel<<<B, TPB, 0, stream>>>(user, out);
    }
}

// Round 4
// 18.791 us; speedup vs baseline: 1.1844x; 1.0174x over previous
//
#include <hip/hip_runtime.h>

// UserMerger — algebraic collapse:
//   triu(MASK_VAL, k=0) masks the diagonal, so diag(softmax)==0 for rows m>=1
//   (exp underflow). Row 0 is fully masked; in fp32, Q_K + (-2^32) rounds every
//   entry to exactly -2^32 (|Q_K| << 128 = half-ulp at that magnitude), so the
//   row softmax is uniform and diag[b,0] == 1/1024 exactly.
//   => out[b,0,d] = sum_m user[b,m,d] / 1024 ; out[b,l>0,:] = 0.
//   W1,b1,W2,b2,hyper_embedding are dead inputs.
//
// R3: fix compile — __builtin_nontemporal_* needs a native vector type, not
// HIP_vector_type<float,4>. Use ext_vector_type(4) float for streamed paths.

namespace {

typedef float f32x4 __attribute__((ext_vector_type(4)));

constexpr int B    = 16;
constexpr int L    = 1024;
constexpr int D    = 512;
constexpr int MG   = 32;        // m-groups per batch
constexpr int MPG  = L / MG;    // 32 rows per group
constexpr int TPBA = D / 4;     // 128 threads: one float4 lane per 4 d's

// Kernel A: partial[b][g][d] = sum_{m in group g} user[b][m][d]
__global__ void partial_sum_kernel(const float* __restrict__ user,
                                   float* __restrict__ partial) {
    const int blk = blockIdx.x;          // b * MG + g
    const int b   = blk >> 5;
    const int g   = blk & (MG - 1);
    const int d4  = threadIdx.x;         // 0..127
    const f32x4* src = reinterpret_cast<const f32x4*>(
        user + (size_t)(b * L + g * MPG) * D) + d4;
    f32x4 acc = (f32x4)(0.f);
#pragma unroll 8
    for (int m = 0; m < MPG; ++m) {
        f32x4 v = __builtin_nontemporal_load(src + (size_t)m * (D / 4));
        acc += v;
    }
    reinterpret_cast<f32x4*>(partial + (size_t)(b * MG + g) * D)[d4] = acc;
}

// Kernel B: zero whole output; blocks owning rows 0..15 of a batch also
// reduce that batch's partials into row 0.
// Grid: B * 64 blocks, 256 threads. Each block covers 16 rows (2048 float4).
__global__ void zero_and_finalize_kernel(const float* __restrict__ partial,
                                         float* __restrict__ out) {
    const int tid = threadIdx.x;
    const int bid = blockIdx.x;
    const int b   = bid >> 6;            // batch
    const int r   = bid & 63;            // row-group of 16 rows
    f32x4* dst = reinterpret_cast<f32x4*>(out + (size_t)(b * L + r * 16) * D);
    const f32x4 z = (f32x4)(0.f);

    if (r != 0) {
#pragma unroll
        for (int it = 0; it < 8; ++it)
            __builtin_nontemporal_store(z, dst + it * 256 + tid);
        return;
    }

    // r == 0: zero rows 1..15 (float4 indices 128..2047)
#pragma unroll
    for (int it = 0; it < 8; ++it) {
        const int idx = it * 256 + tid;
        if (idx >= D / 4)
            __builtin_nontemporal_store(z, dst + idx);
    }

    // Reduce 32 partials for this batch -> row 0 (64 KB, L2/L3-resident).
    const int d4   = tid & (TPBA - 1);   // 0..127
    const int part = tid >> 7;           // 0..1
    const f32x4* p = reinterpret_cast<const f32x4*>(
        partial + (size_t)(b * MG + part * (MG / 2)) * D) + d4;
    f32x4 acc = z;
#pragma unroll
    for (int g = 0; g < MG / 2; ++g)
        acc += p[(size_t)g * (D / 4)];
    __shared__ f32x4 sdata[2][TPBA];
    sdata[part][d4] = acc;
    __syncthreads();
    if (part == 0) {
        f32x4 a0 = sdata[0][d4], a1 = sdata[1][d4];
        const float s = 1.0f / 1024.0f;  // diag of softmax == uniform 1/L
        f32x4 rres = (a0 + a1) * s;
        dst[d4] = rres;
    }
}

// Fallback (only if workspace is unexpectedly tiny): memset + direct reduce.
__global__ void direct_row0_kernel(const float* __restrict__ user,
                                   float* __restrict__ out) {
    const int b  = blockIdx.x;
    const int d4 = threadIdx.x;
    const f32x4* src = reinterpret_cast<const f32x4*>(
        user + (size_t)b * L * D) + d4;
    f32x4 acc = (f32x4)(0.f);
    for (int m = 0; m < L; ++m)
        acc += src[(size_t)m * (D / 4)];
    const float s = 1.0f / 1024.0f;
    acc *= s;
    reinterpret_cast<f32x4*>(out + (size_t)b * L * D)[d4] = acc;
}

} // namespace

extern "C" void kernel_launch(void* const* d_in, const int* in_sizes, int n_in,
                              void* d_out, int out_size, void* d_ws, size_t ws_size,
                              hipStream_t stream) {
    const float* user = (const float*)d_in[0];   // [B, L, D] fp32
    float* out = (float*)d_out;                  // [B, L, D] fp32

    const size_t partial_bytes = (size_t)B * MG * D * sizeof(float); // 1 MiB
    if (ws_size >= partial_bytes) {
        float* partial = (float*)d_ws;
        partial_sum_kernel<<<B * MG, TPBA, 0, stream>>>(user, partial);
        zero_and_finalize_kernel<<<B * 64, 256, 0, stream>>>(partial, out);
    } else {
        (void)hipMemsetAsync(d_out, 0, (size_t)out_size * sizeof(float), stream);
        direct_row0_kernel<<<B, TPBA, 0, stream>>>(user, out);
    }
}